// Round 4
// baseline (2968.645 us; speedup 1.0000x reference)
//
#include <hip/hip_runtime.h>
#include <stdint.h>

// LSTM B=32,T=512,D=1024,H=1024. 2 groups x 16 batches; 128 blocks/group.
// Block = 512 thr (8 waves), owns 8 h-cols (32 gate cols); W slice as f16 MFMA
// B-frags in 128KB LDS. Per-step h exchange through IF with sc0sc1 dwordx4,
// replicated NREP ways to kill coherence-point contention. Wave 0 is the sole
// owner (gates/state/publish); waves 1-7 run ahead into the next step.

typedef _Float16 f16;
typedef __attribute__((ext_vector_type(8))) _Float16 f16x8;
typedef __attribute__((ext_vector_type(4))) float f32x4;
typedef __attribute__((ext_vector_type(4))) unsigned int u32x4;

#define NG 2
#define BPG 128
#define NW 8
#define REPSTRIDE 131072  // 2 parity * 2 G * 32KB

__device__ __forceinline__ float sigm(float v){ return 1.f/(1.f+__expf(-v)); }
__device__ __forceinline__ float tanh_(float v){ return 2.f/(1.f+__expf(-2.f*v)) - 1.f; }

__device__ __forceinline__ u32x4 ld16_sc(const void* p) {
  u32x4 r;
  asm volatile("global_load_dwordx4 %0, %1, off sc0 sc1" : "=v"(r) : "v"(p));
  return r;
}
__device__ __forceinline__ void st16_sc(void* p, u32x4 v) {
  asm volatile("global_store_dwordx4 %0, %1, off sc0 sc1" :: "v"(p), "v"(v) : "memory");
}

__global__ __launch_bounds__(512, 1) void lstm_kernel(
    const float* __restrict__ xin, const float* __restrict__ amask,
    const int* __restrict__ nzidx, const float* __restrict__ Wx,
    const float* __restrict__ Wh, const float* __restrict__ bx,
    const float* __restrict__ bh, float* __restrict__ out,
    uint32_t* __restrict__ ws, int nrep, int flagpg_u32, int h_off_b)
{
  __shared__ __align__(16) f16 Wl[128][64][8];      // 128 KB
  __shared__ __align__(16) float pl[NW][2][64][4];  // 16 KB

  const int tid  = threadIdx.x;
  const int lane = tid & 63;
  const int wid  = tid >> 6;
  const int r    = blockIdx.x & 127;
  const int G    = blockIdx.x >> 7;
  const int hbase = r * 8;
  const int rep_c = r & (nrep - 1);

  uint8_t* hb8 = (uint8_t*)ws + h_off_b;

  // ---- prologue: W slice -> LDS frags (coalesced float4 rows) ----
  {
    const int g = (tid & 7) >> 1, half = tid & 1, row = tid >> 3;
#pragma unroll 1
    for (int it = 0; it < 32; ++it) {
      const int k = it * 64 + row;
      const int side = k >> 10, kk = k & 1023;
      const float* Wsrc = side ? Wh : Wx;
      const f32x4 v = *(const f32x4*)(Wsrc + (size_t)kk * 4096 + g * 1024 + hbase + half * 4);
      const int f = side * 64 + ((kk >> 5) << 1) + (g >> 1);
      const int lane0 = (g & 1) * 8 + half * 4 + 16 * ((kk >> 3) & 3);
      const int e = kk & 7;
#pragma unroll
      for (int i = 0; i < 4; ++i) Wl[f][lane0 + i][e] = (f16)v[i];
    }
  }
  // wave-0 owner state: lane -> (b = lane>>2, hp = lane&3 -> hcols {2hp,2hp+1})
  const int ob = lane >> 2, ohp = lane & 3;
  const int b_glob = G * 16 + ob;
  float bias[4][2];
  float cv0 = 0.f, cv1 = 0.f;
  int myidx = -1;
  if (wid == 0) {
#pragma unroll
    for (int g = 0; g < 4; ++g) {
#pragma unroll
      for (int j = 0; j < 2; ++j) {
        const int gcol = g * 1024 + hbase + ohp * 2 + j;
        bias[g][j] = bx[gcol] + bh[gcol];
      }
    }
    myidx = nzidx[b_glob];
  }
  // preload x(0)
  const int bb = lane & 15, kslot = lane >> 4;
  f32x4 xf[4][2];
  {
    const size_t xrow = ((size_t)(G * 16 + bb) * 512) * 1024;
#pragma unroll
    for (int q = 0; q < 4; ++q) {
      const float* xs = xin + xrow + (wid * 4 + q) * 32 + kslot * 8;
      xf[q][0] = *(const f32x4*)xs;
      xf[q][1] = *(const f32x4*)(xs + 4);
    }
  }
  __syncthreads();

  bool gave_up = false;
#pragma unroll 1
  for (int t = 0; t < 512; ++t) {
    // convert prefetched x -> f16 frags
    f16x8 xa[4];
#pragma unroll
    for (int q = 0; q < 4; ++q) {
      f16x8 a;
#pragma unroll
      for (int i = 0; i < 4; ++i) { a[i] = (f16)xf[q][0][i]; a[i + 4] = (f16)xf[q][1][i]; }
      xa[q] = a;
    }
    f32x4 acc0 = {0.f,0.f,0.f,0.f}, acc1 = {0.f,0.f,0.f,0.f};
#pragma unroll
    for (int q = 0; q < 4; ++q) {
      const int kf = wid * 4 + q;
      f16x8 b0 = *(const f16x8*)&Wl[kf * 2 + 0][lane][0];
      f16x8 b1 = *(const f16x8*)&Wl[kf * 2 + 1][lane][0];
      acc0 = __builtin_amdgcn_mfma_f32_16x16x32_f16(xa[q], b0, acc0, 0, 0, 0);
      acc1 = __builtin_amdgcn_mfma_f32_16x16x32_f16(xa[q], b1, acc1, 0, 0, 0);
    }
    // ---- h phase ----
    if (t > 0) {
      if (!gave_up) {
        const uint32_t tgt = (uint32_t)t;
        const uint32_t* fl = ws + (size_t)rep_c * flagpg_u32 + G * BPG + wid * 16;
        int spins = 0;
        for (;;) {
          uint32_t fv = (lane < 16)
            ? __hip_atomic_load(fl + lane, __ATOMIC_RELAXED, __HIP_MEMORY_SCOPE_AGENT) : tgt;
          if (__all((int)(fv >= tgt))) break;
          if (++spins > (1 << 16)) { gave_up = true; break; }
          __builtin_amdgcn_s_sleep(1);
        }
        __builtin_amdgcn_sched_barrier(0);
      }
      const uint8_t* hrep = hb8 + (size_t)rep_c * REPSTRIDE + ((size_t)((t & 1) * NG + G) << 15);
      u32x4 hq[4];
#pragma unroll
      for (int q = 0; q < 4; ++q)
        hq[q] = ld16_sc(hrep + ((size_t)((wid * 4 + q) * 64 + lane) << 4));
      asm volatile("s_waitcnt vmcnt(0)" ::: "memory");
#pragma unroll
      for (int q = 0; q < 4; ++q) {
        union { u32x4 u; f16x8 v; } cv; cv.u = hq[q];
        const int kf = wid * 4 + q;
        f16x8 b0 = *(const f16x8*)&Wl[64 + kf * 2 + 0][lane][0];
        f16x8 b1 = *(const f16x8*)&Wl[64 + kf * 2 + 1][lane][0];
        acc0 = __builtin_amdgcn_mfma_f32_16x16x32_f16(cv.v, b0, acc0, 0, 0, 0);
        acc1 = __builtin_amdgcn_mfma_f32_16x16x32_f16(cv.v, b1, acc1, 0, 0, 0);
      }
    }
    // issue x(t+1) loads (consumed next iter; off the critical wait)
    if (t + 1 < 512) {
      const size_t xrow = ((size_t)(G * 16 + bb) * 512 + (size_t)(t + 1)) * 1024;
#pragma unroll
      for (int q = 0; q < 4; ++q) {
        const float* xs = xin + xrow + (wid * 4 + q) * 32 + kslot * 8;
        xf[q][0] = *(const f32x4*)xs;
        xf[q][1] = *(const f32x4*)(xs + 4);
      }
    }
    *(f32x4*)&pl[wid][0][lane][0] = acc0;
    *(f32x4*)&pl[wid][1][lane][0] = acc1;
    __syncthreads();  // sync1: pl ready
    // ---- wave0 owner: reduce ----
    float ssum[4][2];
    if (wid == 0) {
#pragma unroll
      for (int g = 0; g < 4; ++g) {
#pragma unroll
        for (int j = 0; j < 2; ++j) {
          const int lp = (g & 1) * 8 + (ohp * 2 + j) + 16 * (ob >> 2);
          const int reg = ob & 3;
          float v = bias[g][j];
#pragma unroll
          for (int w = 0; w < NW; ++w) v += pl[w][g >> 1][lp][reg];
          ssum[g][j] = v;
        }
      }
    }
    __syncthreads();  // sync2: pl consumed; waves 1-7 sprint into t+1
    if (wid == 0) {
      const float i0 = sigm(ssum[0][0]), i1 = sigm(ssum[0][1]);
      const float f0 = sigm(ssum[1][0]), f1 = sigm(ssum[1][1]);
      const float g0 = tanh_(ssum[2][0]), g1 = tanh_(ssum[2][1]);
      const float o0 = sigm(ssum[3][0]), o1 = sigm(ssum[3][1]);
      cv0 = f0 * cv0 + i0 * g0;
      cv1 = f1 * cv1 + i1 * g1;
      const float hv0 = o0 * tanh_(cv0);
      const float hv1 = o1 * tanh_(cv1);
      union { f16 h[2]; uint32_t u; } pk;
      pk.h[0] = (f16)hv0; pk.h[1] = (f16)hv1;
      // gather the 4 hp-words of this batch into a 16B quad (order-fixed per lane)
      const uint32_t v0 = pk.u;
      const uint32_t v1 = __shfl_xor((int)v0 * 0 + (int)pk.u, 1, 64);
      const uint32_t v2 = __shfl_xor((int)pk.u, 2, 64);
      const uint32_t v3 = __shfl_xor((int)pk.u, 3, 64);
      const uint32_t t0 = (ohp & 1) ? v1 : v0, t1 = (ohp & 1) ? v0 : v1;
      const uint32_t t2 = (ohp & 1) ? v3 : v2, t3 = (ohp & 1) ? v2 : v3;
      u32x4 quad;
      quad[0] = (ohp & 2) ? t2 : t0; quad[1] = (ohp & 2) ? t3 : t1;
      quad[2] = (ohp & 2) ? t0 : t2; quad[3] = (ohp & 2) ? t1 : t3;
      if (t < 511) {
        const size_t unit = (size_t)((r >> 2) * 64 + ob + 16 * (r & 3)) << 4;
        const size_t poff = (size_t)(((t + 1) & 1) * NG + G) << 15;
        if (ohp < nrep)
          st16_sc(hb8 + (size_t)ohp * REPSTRIDE + poff + unit, quad);
        if (ohp + 4 < nrep)
          st16_sc(hb8 + (size_t)(ohp + 4) * REPSTRIDE + poff + unit, quad);
        asm volatile("s_waitcnt vmcnt(0)" ::: "memory");
        if (lane < nrep)
          __hip_atomic_store(ws + (size_t)lane * flagpg_u32 + G * BPG + r, (uint32_t)(t + 1),
                             __ATOMIC_RELAXED, __HIP_MEMORY_SCOPE_AGENT);
      }
      // outputs (off the sync path)
      const float mval = amask[(size_t)b_glob * 512 + (size_t)t];
      const size_t o0p = ((size_t)b_glob * 512 + (size_t)t) * 1024 + (size_t)(hbase + ohp * 2);
      const float2 hm = {hv0 * mval, hv1 * mval};
      const float2 cm = {cv0 * mval, cv1 * mval};
      *(float2*)(out + o0p) = hm;
      *(float2*)(out + o0p + 16777216u) = hm;
      *(float2*)(out + o0p + 33554432u) = cm;
      if (t == myidx) {
        const float2 hr = {hv0, hv1};
        *(float2*)(out + 50331648u + (size_t)b_glob * 1024 + (size_t)(hbase + ohp * 2)) = hr;
      }
    }
  }
}

extern "C" void kernel_launch(void* const* d_in, const int* in_sizes, int n_in,
                              void* d_out, int out_size, void* d_ws, size_t ws_size,
                              hipStream_t stream) {
  const float* xin   = (const float*)d_in[0];
  const float* amask = (const float*)d_in[1];
  const int*   nzidx = (const int*)d_in[2];
  const float* Wx    = (const float*)d_in[3];
  const float* Wh    = (const float*)d_in[4];
  const float* bx    = (const float*)d_in[5];
  const float* bh    = (const float*)d_in[6];
  float* out = (float*)d_out;
  uint32_t* ws = (uint32_t*)d_ws;

  // size replication to the workspace we actually have
  size_t flagpg = 4096; int nrep = 8;
  while (nrep > 1 && ws_size < (size_t)nrep * (flagpg + REPSTRIDE)) nrep >>= 1;
  if (ws_size < flagpg + REPSTRIDE) flagpg = 1024;  // proven-floor compact layout
  int flagpg_u32 = (int)(flagpg / 4);
  int h_off_b = (int)((size_t)nrep * flagpg);

  hipMemsetAsync(d_ws, 0, (size_t)nrep * flagpg, stream);

  void* args[] = {(void*)&xin, (void*)&amask, (void*)&nzidx, (void*)&Wx,
                  (void*)&Wh, (void*)&bx, (void*)&bh, (void*)&out, (void*)&ws,
                  (void*)&nrep, (void*)&flagpg_u32, (void*)&h_off_b};
  hipError_t e = hipLaunchCooperativeKernel((const void*)lstm_kernel, dim3(256), dim3(512),
                                            args, 0, stream);
  if (e != hipSuccess) {
    lstm_kernel<<<dim3(256), dim3(512), 0, stream>>>(xin, amask, nzidx, Wx, Wh, bx, bh,
                                                     out, ws, nrep, flagpg_u32, h_off_b);
  }
}

// Round 5
// 2460.992 us; speedup vs baseline: 1.2063x; 1.2063x over previous
//
#include <hip/hip_runtime.h>
#include <stdint.h>

// LSTM B=32,T=512,D=1024,H=1024. 2 groups x 16 batches; 128 blocks/group.
// Block = 512 thr (8 waves), owns 8 h-cols (32 gate cols); W slice as f16 MFMA
// B-frags in 128KB LDS. Per-step h exchange through IF with TAG-IN-DATA:
// each 16B store = [2 data words][step tag][pad]; consumers speculatively load
// and validate tags -> wait and load are ONE IF hop; producers need no
// vmcnt/flag (unit valid iff both half-tags match; parity double-buffer +
// publish-after-consume ordering makes overwrite safe).

typedef _Float16 f16;
typedef __attribute__((ext_vector_type(8))) _Float16 f16x8;
typedef __attribute__((ext_vector_type(4))) float f32x4;
typedef __attribute__((ext_vector_type(4))) unsigned int u32x4;

#define NG 2
#define NW 8
#define HBYTES (2 * NG * 2048 * 32)  // 262144: 2 parity x 2 groups x 2048 units x 32B

__device__ __forceinline__ float sigm(float v){ return 1.f/(1.f+__expf(-v)); }
__device__ __forceinline__ float tanh_(float v){ return 2.f/(1.f+__expf(-2.f*v)) - 1.f; }

__device__ __forceinline__ u32x4 ld16_sc(const void* p) {
  u32x4 r;
  asm volatile("global_load_dwordx4 %0, %1, off sc0 sc1" : "=v"(r) : "v"(p));
  return r;
}
__device__ __forceinline__ void st16_sc(void* p, u32x4 v) {
  asm volatile("global_store_dwordx4 %0, %1, off sc0 sc1" :: "v"(p), "v"(v) : "memory");
}

__global__ __launch_bounds__(512, 1) void lstm_kernel(
    const float* __restrict__ xin, const float* __restrict__ amask,
    const int* __restrict__ nzidx, const float* __restrict__ Wx,
    const float* __restrict__ Wh, const float* __restrict__ bx,
    const float* __restrict__ bh, float* __restrict__ out,
    uint32_t* __restrict__ ws)
{
  // frag f = side*64 + kf*2 + nt  (side: 0=x,1=h; kf 0..31; nt 0..1)
  __shared__ __align__(16) f16 Wl[128][64][8];      // 128 KB
  __shared__ __align__(16) float pl[NW][2][64][4];  // 16 KB
  __shared__ __align__(16) f16 hstage[16][8];       // 256 B

  const int tid  = threadIdx.x;
  const int lane = tid & 63;
  const int wid  = tid >> 6;
  const int r    = blockIdx.x & 127;
  const int G    = blockIdx.x >> 7;
  const int hbase = r * 8;

  uint8_t* hb8 = (uint8_t*)ws;

  // ---- prologue: W slice -> LDS frags (round-3 proven, conflict-free) ----
  for (int f = wid; f < 128; f += NW) {
    const int side = f >> 6, kf = (f >> 1) & 31, nt = f & 1;
    const int c16 = lane & 15, kslot = lane >> 4;
    const int g = nt * 2 + (c16 >> 3);
    const int gcol = g * 1024 + hbase + (c16 & 7);
    const int k0 = kf * 32 + kslot * 8;
    const float* Wsrc = side ? Wh : Wx;
    f16x8 v;
#pragma unroll
    for (int e = 0; e < 8; ++e) v[e] = (f16)Wsrc[(size_t)(k0 + e) * 4096 + gcol];
    *(f16x8*)&Wl[f][lane][0] = v;
  }
  // owner state (tid<128): owner = (batch b, h-col hc)
  const int b  = tid >> 3;
  const int hc = tid & 7;
  const int b_glob = G * 16 + b;
  float bias[4] = {0.f, 0.f, 0.f, 0.f};
  float cval = 0.f;
  int myidx = -1;
  if (tid < 128) {
#pragma unroll
    for (int g = 0; g < 4; ++g) {
      const int gcol = g * 1024 + hbase + hc;
      bias[g] = bx[gcol] + bh[gcol];
    }
    myidx = nzidx[b_glob];
  }
  // preload x(0) into regs
  const int bb = lane & 15, kslot = lane >> 4;
  f32x4 xf[4][2];
  {
    const size_t xrow = ((size_t)(G * 16 + bb) * 512) * 1024;
#pragma unroll
    for (int q = 0; q < 4; ++q) {
      const float* xs = xin + xrow + (wid * 4 + q) * 32 + kslot * 8;
      xf[q][0] = *(const f32x4*)xs;
      xf[q][1] = *(const f32x4*)(xs + 4);
    }
  }
  __syncthreads();

  bool gave_up = false;
#pragma unroll 1
  for (int t = 0; t < 512; ++t) {
    // ---- x-side MFMAs from prefetched regs ----
    f16x8 xa[4];
#pragma unroll
    for (int q = 0; q < 4; ++q) {
      f16x8 a;
#pragma unroll
      for (int i = 0; i < 4; ++i) { a[i] = (f16)xf[q][0][i]; a[i + 4] = (f16)xf[q][1][i]; }
      xa[q] = a;
    }
    f32x4 acc0 = {0.f,0.f,0.f,0.f}, acc1 = {0.f,0.f,0.f,0.f};
#pragma unroll
    for (int q = 0; q < 4; ++q) {
      const int kf = wid * 4 + q;
      f16x8 b0 = *(const f16x8*)&Wl[kf * 2 + 0][lane][0];
      f16x8 b1 = *(const f16x8*)&Wl[kf * 2 + 1][lane][0];
      acc0 = __builtin_amdgcn_mfma_f32_16x16x32_f16(xa[q], b0, acc0, 0, 0, 0);
      acc1 = __builtin_amdgcn_mfma_f32_16x16x32_f16(xa[q], b1, acc1, 0, 0, 0);
    }
    // ---- h-side: tagged speculative load == wait (one IF hop) ----
    if (t > 0) {
      const uint8_t* hsrc = hb8 + ((size_t)((t & 1) * NG + G) << 16);
      u32x4 ha[4], hbq[4];
      int spins = 0;
      for (;;) {
#pragma unroll
        for (int q = 0; q < 4; ++q) {
          const uint8_t* up = hsrc + (((size_t)(wid * 4 + q) * 64 + lane) << 5);
          ha[q]  = ld16_sc(up);
          hbq[q] = ld16_sc(up + 16);
        }
        asm volatile("s_waitcnt vmcnt(0)" ::: "memory");
        if (gave_up) break;
        uint32_t tmin = ha[0][2];
#pragma unroll
        for (int q = 0; q < 4; ++q) {
          tmin = tmin < ha[q][2]  ? tmin : ha[q][2];
          tmin = tmin < hbq[q][2] ? tmin : hbq[q][2];
        }
        if (__all((int)(tmin >= (uint32_t)t))) break;
        if (++spins > (1 << 13)) { gave_up = true; break; }  // latched safety valve
        __builtin_amdgcn_s_sleep(1);
      }
      __builtin_amdgcn_sched_barrier(0);
#pragma unroll
      for (int q = 0; q < 4; ++q) {
        union { u32x4 u; f16x8 v; } cv;
        cv.u[0] = ha[q][0]; cv.u[1] = ha[q][1];
        cv.u[2] = hbq[q][0]; cv.u[3] = hbq[q][1];
        const int kf = wid * 4 + q;
        f16x8 b0 = *(const f16x8*)&Wl[64 + kf * 2 + 0][lane][0];
        f16x8 b1 = *(const f16x8*)&Wl[64 + kf * 2 + 1][lane][0];
        acc0 = __builtin_amdgcn_mfma_f32_16x16x32_f16(cv.v, b0, acc0, 0, 0, 0);
        acc1 = __builtin_amdgcn_mfma_f32_16x16x32_f16(cv.v, b1, acc1, 0, 0, 0);
      }
    }
    // issue x(t+1) prefetch (normal loads, off the critical wait)
    if (t + 1 < 512) {
      const size_t xrow = ((size_t)(G * 16 + bb) * 512 + (size_t)(t + 1)) * 1024;
#pragma unroll
      for (int q = 0; q < 4; ++q) {
        const float* xs = xin + xrow + (wid * 4 + q) * 32 + kslot * 8;
        xf[q][0] = *(const f32x4*)xs;
        xf[q][1] = *(const f32x4*)(xs + 4);
      }
    }
    *(f32x4*)&pl[wid][0][lane][0] = acc0;
    *(f32x4*)&pl[wid][1][lane][0] = acc1;
    __syncthreads();  // sync1: pl ready
    // ---- owners: reduce, gates, state ----
    float hval = 0.f, mval = 0.f;
    if (tid < 128) {
      float s[4];
#pragma unroll
      for (int g = 0; g < 4; ++g) {
        const int lp = ((g & 1) * 8 + hc) + 16 * (b >> 2);
        const int reg = b & 3;
        float v = bias[g];
#pragma unroll
        for (int w = 0; w < NW; ++w) v += pl[w][g >> 1][lp][reg];
        s[g] = v;
      }
      const float ig = sigm(s[0]);
      const float fg = sigm(s[1]);
      const float gg = tanh_(s[2]);
      const float og = sigm(s[3]);
      cval = fg * cval + ig * gg;
      hval = og * tanh_(cval);
      hstage[b][hc] = (f16)hval;
      mval = amask[(size_t)b_glob * 512 + (size_t)t];
    }
    __syncthreads();  // sync2: hstage ready
    // ---- publish: 32 tagged 16B stores, fire-and-forget (no vmcnt, no flag) ----
    if (wid == 0 && lane < 32 && t < 511) {
      const int ob = lane >> 1, half = lane & 1;
      const uint32_t* hrow = (const uint32_t*)&hstage[ob][half * 4];
      u32x4 q;
      q[0] = hrow[0]; q[1] = hrow[1]; q[2] = (uint32_t)(t + 1); q[3] = 0u;
      const size_t unit = (size_t)((r >> 2) * 64 + (r & 3) * 16 + ob);
      uint8_t* dst = hb8 + ((size_t)(((t + 1) & 1) * NG + G) << 16) + unit * 32 + half * 16;
      st16_sc(dst, q);
    }
    // ---- outputs (off the sync critical path) ----
    if (tid < 128) {
      const size_t o0 = ((size_t)b_glob * 512 + (size_t)t) * 1024 + (size_t)(hbase + hc);
      out[o0] = hval * mval;                   // hts copy 1
      out[o0 + 16777216u] = hval * mval;       // hts copy 2
      out[o0 + 33554432u] = cval * mval;       // cts
      if (t == myidx) out[50331648u + (size_t)b_glob * 1024 + (size_t)(hbase + hc)] = hval;
    }
  }
}

extern "C" void kernel_launch(void* const* d_in, const int* in_sizes, int n_in,
                              void* d_out, int out_size, void* d_ws, size_t ws_size,
                              hipStream_t stream) {
  const float* xin   = (const float*)d_in[0];
  const float* amask = (const float*)d_in[1];
  const int*   nzidx = (const int*)d_in[2];
  const float* Wx    = (const float*)d_in[3];
  const float* Wh    = (const float*)d_in[4];
  const float* bx    = (const float*)d_in[5];
  const float* bh    = (const float*)d_in[6];
  float* out = (float*)d_out;
  uint32_t* ws = (uint32_t*)d_ws;

  // zero the tagged h-buffer every launch (kills stale tags across graph replays)
  hipMemsetAsync(d_ws, 0, HBYTES, stream);

  void* args[] = {(void*)&xin, (void*)&amask, (void*)&nzidx, (void*)&Wx,
                  (void*)&Wh, (void*)&bx, (void*)&bh, (void*)&out, (void*)&ws};
  hipError_t e = hipLaunchCooperativeKernel((const void*)lstm_kernel, dim3(256), dim3(512),
                                            args, 0, stream);
  if (e != hipSuccess) {
    lstm_kernel<<<dim3(256), dim3(512), 0, stream>>>(xin, amask, nzidx, Wx, Wh, bx, bh, out, ws);
  }
}

// Round 6
// 2231.289 us; speedup vs baseline: 1.3305x; 1.1029x over previous
//
#include <hip/hip_runtime.h>
#include <stdint.h>

// LSTM B=32,T=512,D=1024,H=1024. 2 groups x 16 batches; 128 blocks/group.
// Block = 512 thr (8 waves), owns 8 h-cols (32 gate cols); W slice as f16 MFMA
// B-frags in 128KB LDS. Per-step h exchange through IF with STEGANOGRAPHIC
// tags: low mantissa bit of each f16 carries a 2-bit step counter per dword
// (tearing-safe), so 16B units stay 16B, detection==load (one IF hop), and
// producers publish with single fire-and-forget 2B stores per owner (no
// vmcnt, no flags, no hstage hop).

typedef _Float16 f16;
typedef __attribute__((ext_vector_type(8))) _Float16 f16x8;
typedef __attribute__((ext_vector_type(4))) float f32x4;
typedef __attribute__((ext_vector_type(4))) unsigned int u32x4;

#define NG 2
#define NW 8
#define HBYTES (2 * NG * 2048 * 16)  // 131072: 2 parity x 2 groups x 2048 units x 16B

__device__ __forceinline__ float sigm(float v){ return 1.f/(1.f+__expf(-v)); }
__device__ __forceinline__ float tanh_(float v){ return 2.f/(1.f+__expf(-2.f*v)) - 1.f; }

__device__ __forceinline__ u32x4 ld16_sc(const void* p) {
  u32x4 r;
  asm volatile("global_load_dwordx4 %0, %1, off sc0 sc1" : "=v"(r) : "v"(p));
  return r;
}
__device__ __forceinline__ void st2_sc(void* p, uint32_t v) {
  asm volatile("global_store_short %0, %1, off sc0 sc1" :: "v"(p), "v"(v) : "memory");
}

__global__ __launch_bounds__(512, 1) void lstm_kernel(
    const float* __restrict__ xin, const float* __restrict__ amask,
    const int* __restrict__ nzidx, const float* __restrict__ Wx,
    const float* __restrict__ Wh, const float* __restrict__ bx,
    const float* __restrict__ bh, float* __restrict__ out,
    uint32_t* __restrict__ ws)
{
  // frag f = side*64 + kf*2 + nt  (side: 0=x,1=h; kf 0..31; nt 0..1)
  __shared__ __align__(16) f16 Wl[128][64][8];      // 128 KB
  __shared__ __align__(16) float pl[NW][2][64][4];  // 16 KB

  const int tid  = threadIdx.x;
  const int lane = tid & 63;
  const int wid  = tid >> 6;
  const int r    = blockIdx.x & 127;
  const int G    = blockIdx.x >> 7;
  const int hbase = r * 8;

  uint8_t* hb8 = (uint8_t*)ws;

  // ---- prologue: W slice -> LDS frags (round-3 proven, conflict-free) ----
  for (int f = wid; f < 128; f += NW) {
    const int side = f >> 6, kf = (f >> 1) & 31, nt = f & 1;
    const int c16 = lane & 15, kslot = lane >> 4;
    const int g = nt * 2 + (c16 >> 3);
    const int gcol = g * 1024 + hbase + (c16 & 7);
    const int k0 = kf * 32 + kslot * 8;
    const float* Wsrc = side ? Wh : Wx;
    f16x8 v;
#pragma unroll
    for (int e = 0; e < 8; ++e) v[e] = (f16)Wsrc[(size_t)(k0 + e) * 4096 + gcol];
    *(f16x8*)&Wl[f][lane][0] = v;
  }
  // owner state (tid<128): owner = (batch b, h-col hc)
  const int b  = tid >> 3;
  const int hc = tid & 7;
  const int b_glob = G * 16 + b;
  float bias[4] = {0.f, 0.f, 0.f, 0.f};
  float cval = 0.f;
  int myidx = -1;
  if (tid < 128) {
#pragma unroll
    for (int g = 0; g < 4; ++g) {
      const int gcol = g * 1024 + hbase + hc;
      bias[g] = bx[gcol] + bh[gcol];
    }
    myidx = nzidx[b_glob];
  }
  // preload x(0) into regs
  const int bb = lane & 15, kslot = lane >> 4;
  f32x4 xf[4][2];
  {
    const size_t xrow = ((size_t)(G * 16 + bb) * 512) * 1024;
#pragma unroll
    for (int q = 0; q < 4; ++q) {
      const float* xs = xin + xrow + (wid * 4 + q) * 32 + kslot * 8;
      xf[q][0] = *(const f32x4*)xs;
      xf[q][1] = *(const f32x4*)(xs + 4);
    }
  }
  __syncthreads();

  bool gave_up = false;
#pragma unroll 1
  for (int t = 0; t < 512; ++t) {
    // ---- x-side MFMAs from prefetched regs ----
    f16x8 xa[4];
#pragma unroll
    for (int q = 0; q < 4; ++q) {
      f16x8 a;
#pragma unroll
      for (int i = 0; i < 4; ++i) { a[i] = (f16)xf[q][0][i]; a[i + 4] = (f16)xf[q][1][i]; }
      xa[q] = a;
    }
    f32x4 acc0 = {0.f,0.f,0.f,0.f}, acc1 = {0.f,0.f,0.f,0.f};
#pragma unroll
    for (int q = 0; q < 4; ++q) {
      const int kf = wid * 4 + q;
      f16x8 b0 = *(const f16x8*)&Wl[kf * 2 + 0][lane][0];
      f16x8 b1 = *(const f16x8*)&Wl[kf * 2 + 1][lane][0];
      acc0 = __builtin_amdgcn_mfma_f32_16x16x32_f16(xa[q], b0, acc0, 0, 0, 0);
      acc1 = __builtin_amdgcn_mfma_f32_16x16x32_f16(xa[q], b1, acc1, 0, 0, 0);
    }
    // issue x(t+1) prefetch BEFORE the wait (drains inside the spin)
    if (t + 1 < 512) {
      const size_t xrow = ((size_t)(G * 16 + bb) * 512 + (size_t)(t + 1)) * 1024;
#pragma unroll
      for (int q = 0; q < 4; ++q) {
        const float* xs = xin + xrow + (wid * 4 + q) * 32 + kslot * 8;
        xf[q][0] = *(const f32x4*)xs;
        xf[q][1] = *(const f32x4*)(xs + 4);
      }
    }
    // ---- h-side: speculative tagged load == wait (16B units, one IF hop) ----
    if (t > 0) {
      const uint8_t* hsrc = hb8 + ((size_t)((t & 1) * NG + G) << 15);
      const uint32_t tb = ((uint32_t)(t >> 1) + 1u) & 3u;
      const uint32_t pat = (tb & 1u) | ((tb >> 1) << 16);
      u32x4 hq[4];
      int spins = 0;
      for (;;) {
#pragma unroll
        for (int q = 0; q < 4; ++q) {
          const int rsrc = (wid * 4 + q) * 4 + kslot;   // producer rank owning these 8 cols
          hq[q] = ld16_sc(hsrc + ((size_t)(rsrc * 16 + bb) << 4));
        }
        asm volatile("s_waitcnt vmcnt(0)" ::: "memory");
        if (gave_up) break;
        bool ok = true;
#pragma unroll
        for (int q = 0; q < 4; ++q) {
#pragma unroll
          for (int j = 0; j < 4; ++j) ok &= ((hq[q][j] & 0x00010001u) == pat);
        }
        if (__all((int)ok)) break;
        if (++spins > (1 << 13)) { gave_up = true; break; }  // latched safety valve
        __builtin_amdgcn_s_sleep(1);
      }
#pragma unroll
      for (int q = 0; q < 4; ++q) {
        union { u32x4 u; f16x8 v; } cu; cu.u = hq[q];
        const int kf = wid * 4 + q;
        f16x8 b0 = *(const f16x8*)&Wl[64 + kf * 2 + 0][lane][0];
        f16x8 b1 = *(const f16x8*)&Wl[64 + kf * 2 + 1][lane][0];
        acc0 = __builtin_amdgcn_mfma_f32_16x16x32_f16(cu.v, b0, acc0, 0, 0, 0);
        acc1 = __builtin_amdgcn_mfma_f32_16x16x32_f16(cu.v, b1, acc1, 0, 0, 0);
      }
    }
    *(f32x4*)&pl[wid][0][lane][0] = acc0;
    *(f32x4*)&pl[wid][1][lane][0] = acc1;
    __syncthreads();  // sync1: pl ready
    // ---- owners: reduce, gates, state, PUBLISH, outputs ----
    if (tid < 128) {
      float s[4];
#pragma unroll
      for (int g = 0; g < 4; ++g) {
        const int lp = ((g & 1) * 8 + hc) + 16 * (b >> 2);
        const int reg = b & 3;
        float v = bias[g];
#pragma unroll
        for (int w = 0; w < NW; ++w) v += pl[w][g >> 1][lp][reg];
        s[g] = v;
      }
      const float ig = sigm(s[0]);
      const float fg = sigm(s[1]);
      const float gg = tanh_(s[2]);
      const float og = sigm(s[3]);
      cval = fg * cval + ig * gg;
      const float hval = og * tanh_(cval);
      // publish: single 2B tagged store, fire-and-forget
      if (t < 511) {
        union { f16 f; uint16_t u; } pk; pk.f = (f16)hval;
        const uint32_t tbp = ((uint32_t)((t + 1) >> 1) + 1u) & 3u;
        const uint32_t bitv = (hc & 1) ? ((tbp >> 1) & 1u) : (tbp & 1u);
        const uint32_t val = ((uint32_t)pk.u & 0xFFFEu) | bitv;
        uint8_t* dst = hb8 + ((size_t)(((t + 1) & 1) * NG + G) << 15)
                     + ((size_t)(r * 16 + b) << 4) + (hc << 1);
        st2_sc(dst, val);
      }
      // outputs (off the sync critical path)
      const float mval = amask[(size_t)b_glob * 512 + (size_t)t];
      const size_t o0 = ((size_t)b_glob * 512 + (size_t)t) * 1024 + (size_t)(hbase + hc);
      out[o0] = hval * mval;                   // hts copy 1
      out[o0 + 16777216u] = hval * mval;       // hts copy 2
      out[o0 + 33554432u] = cval * mval;       // cts
      if (t == myidx) out[50331648u + (size_t)b_glob * 1024 + (size_t)(hbase + hc)] = hval;
    }
    __syncthreads();  // sync2: pl consumed; waves may write pl for t+1
  }
}

extern "C" void kernel_launch(void* const* d_in, const int* in_sizes, int n_in,
                              void* d_out, int out_size, void* d_ws, size_t ws_size,
                              hipStream_t stream) {
  const float* xin   = (const float*)d_in[0];
  const float* amask = (const float*)d_in[1];
  const int*   nzidx = (const int*)d_in[2];
  const float* Wx    = (const float*)d_in[3];
  const float* Wh    = (const float*)d_in[4];
  const float* bx    = (const float*)d_in[5];
  const float* bh    = (const float*)d_in[6];
  float* out = (float*)d_out;
  uint32_t* ws = (uint32_t*)d_ws;

  // zero the tagged h-buffer every launch (stale tags differ from t=1/t=2 expectations)
  hipMemsetAsync(d_ws, 0, HBYTES, stream);

  void* args[] = {(void*)&xin, (void*)&amask, (void*)&nzidx, (void*)&Wx,
                  (void*)&Wh, (void*)&bx, (void*)&bh, (void*)&out, (void*)&ws};
  hipError_t e = hipLaunchCooperativeKernel((const void*)lstm_kernel, dim3(256), dim3(512),
                                            args, 0, stream);
  if (e != hipSuccess) {
    lstm_kernel<<<dim3(256), dim3(512), 0, stream>>>(xin, amask, nzidx, Wx, Wh, bx, bh, out, ws);
  }
}

// Round 8
// 2098.459 us; speedup vs baseline: 1.4147x; 1.0633x over previous
//
#include <hip/hip_runtime.h>
#include <stdint.h>

// LSTM B=32,T=512,D=1024,H=1024. 2 groups x 16 batches; 128 blocks/group.
// Block = 512 thr (8 waves), owns 8 h-cols (32 gate cols); W slice as f16 MFMA
// B-frags in 128KB LDS. h exchange: stego-tagged 16B units in IF (low mantissa
// bit of each f16 = 2-bit step counter per dword). Round 8: single-stream
// probes (ALWAYS vmcnt(0)-drained before use -- R7's counted-wait left loads
// in flight past register death -> clobber -> NaN), issued EARLY so flight
// hides under x-MFMAs; x(t+1)/amask prefetch moved off the probe drains;
// ONE barrier per step via pl[2] parity ping-pong (waves 2-7 sprint ahead).

typedef _Float16 f16;
typedef __attribute__((ext_vector_type(8))) _Float16 f16x8;
typedef __attribute__((ext_vector_type(4))) float f32x4;
typedef __attribute__((ext_vector_type(4))) unsigned int u32x4;

#define NG 2
#define NW 8
#define HBYTES (2 * NG * 2048 * 16)  // 131072

__device__ __forceinline__ float sigm(float v){ return 1.f/(1.f+__expf(-v)); }
__device__ __forceinline__ float tanh_(float v){ return 2.f/(1.f+__expf(-2.f*v)) - 1.f; }

__device__ __forceinline__ u32x4 ld16_sc(const void* p) {
  u32x4 r;
  asm volatile("global_load_dwordx4 %0, %1, off sc0 sc1" : "=v"(r) : "v"(p));
  return r;
}
__device__ __forceinline__ void st2_sc(void* p, uint32_t v) {
  asm volatile("global_store_short %0, %1, off sc0 sc1" :: "v"(p), "v"(v) : "memory");
}

__global__ __launch_bounds__(512, 1) void lstm_kernel(
    const float* __restrict__ xin, const float* __restrict__ amask,
    const int* __restrict__ nzidx, const float* __restrict__ Wx,
    const float* __restrict__ Wh, const float* __restrict__ bx,
    const float* __restrict__ bh, float* __restrict__ out,
    uint32_t* __restrict__ ws)
{
  // frag f = side*64 + kf*2 + nt  (side: 0=x,1=h; kf 0..31; nt 0..1)
  __shared__ __align__(16) f16 Wl[128][64][8];         // 128 KB
  __shared__ __align__(16) float pl[2][NW][2][64][4];  // 32 KB (parity ping-pong)

  const int tid  = threadIdx.x;
  const int lane = tid & 63;
  const int wid  = tid >> 6;
  const int r    = blockIdx.x & 127;
  const int G    = blockIdx.x >> 7;
  const int hbase = r * 8;

  uint8_t* hb8 = (uint8_t*)ws;

  // ---- prologue: W slice -> LDS frags (round-3 proven, conflict-free) ----
  for (int f = wid; f < 128; f += NW) {
    const int side = f >> 6, kf = (f >> 1) & 31, nt = f & 1;
    const int c16 = lane & 15, kslot_ = lane >> 4;
    const int g = nt * 2 + (c16 >> 3);
    const int gcol = g * 1024 + hbase + (c16 & 7);
    const int k0 = kf * 32 + kslot_ * 8;
    const float* Wsrc = side ? Wh : Wx;
    f16x8 v;
#pragma unroll
    for (int e = 0; e < 8; ++e) v[e] = (f16)Wsrc[(size_t)(k0 + e) * 4096 + gcol];
    *(f16x8*)&Wl[f][lane][0] = v;
  }
  // owner state (tid<128): owner = (batch b, h-col hc)
  const int b  = tid >> 3;
  const int hc = tid & 7;
  const int b_glob = G * 16 + b;
  float bias[4] = {0.f, 0.f, 0.f, 0.f};
  float cval = 0.f, mv_cur = 0.f;
  int myidx = -1;
  if (tid < 128) {
#pragma unroll
    for (int g = 0; g < 4; ++g) {
      const int gcol = g * 1024 + hbase + hc;
      bias[g] = bx[gcol] + bh[gcol];
    }
    myidx = nzidx[b_glob];
    mv_cur = amask[(size_t)b_glob * 512];
  }
  // preload x(0) into regs
  const int bb = lane & 15, kslot = lane >> 4;
  f32x4 xf[4][2];
  {
    const size_t xrow = ((size_t)(G * 16 + bb) * 512) * 1024;
#pragma unroll
    for (int q = 0; q < 4; ++q) {
      const float* xs = xin + xrow + (wid * 4 + q) * 32 + kslot * 8;
      xf[q][0] = *(const f32x4*)xs;
      xf[q][1] = *(const f32x4*)(xs + 4);
    }
  }
  __syncthreads();

  bool gave_up = false;
#pragma unroll 1
  for (int t = 0; t < 512; ++t) {
    const int ppl = t & 1;
    // ---- convert x(t) regs -> f16 frags (compiler drains xf loads here) ----
    f16x8 xa[4];
#pragma unroll
    for (int q = 0; q < 4; ++q) {
      f16x8 a;
#pragma unroll
      for (int i = 0; i < 4; ++i) { a[i] = (f16)xf[q][0][i]; a[i + 4] = (f16)xf[q][1][i]; }
      xa[q] = a;
    }
    // ---- EARLY probe issue: flight hides under x-MFMAs ----
    const uint8_t* hsrc = hb8 + ((size_t)((t & 1) * NG + G) << 15);
    uint32_t pat = 0;
    size_t aoff[4];
    u32x4 hq[4];
    if (t > 0) {
      const uint32_t tb = ((uint32_t)(t >> 1) + 1u) & 3u;
      pat = (tb & 1u) | (((tb >> 1) & 1u) << 16);
#pragma unroll
      for (int q = 0; q < 4; ++q) {
        const int rsrc = (wid * 4 + q) * 4 + kslot;   // producer rank of these 8 cols
        aoff[q] = (size_t)(rsrc * 16 + bb) << 4;
        hq[q] = ld16_sc(hsrc + aoff[q]);
      }
    }
    // ---- x-side MFMAs (register + LDS only; no vmem between issue and drain) ----
    f32x4 acc0 = {0.f,0.f,0.f,0.f}, acc1 = {0.f,0.f,0.f,0.f};
#pragma unroll
    for (int q = 0; q < 4; ++q) {
      const int kf = wid * 4 + q;
      f16x8 b0 = *(const f16x8*)&Wl[kf * 2 + 0][lane][0];
      f16x8 b1 = *(const f16x8*)&Wl[kf * 2 + 1][lane][0];
      acc0 = __builtin_amdgcn_mfma_f32_16x16x32_f16(xa[q], b0, acc0, 0, 0, 0);
      acc1 = __builtin_amdgcn_mfma_f32_16x16x32_f16(xa[q], b1, acc1, 0, 0, 0);
    }
    if (t > 0) {
      // ---- spin: drain-check-reissue (period = RTT, no sleep) ----
      if (!gave_up) {
        bool got = false;
        int spins = 0;
        for (;;) {
          asm volatile("s_waitcnt vmcnt(0)" ::: "memory");
          __builtin_amdgcn_sched_barrier(0);
          bool ok = true;
#pragma unroll
          for (int q = 0; q < 4; ++q)
#pragma unroll
            for (int j = 0; j < 4; ++j) ok &= ((hq[q][j] & 0x00010001u) == pat);
          if (__all((int)ok)) { got = true; break; }
          if (++spins > (1 << 14)) break;   // safety valve (terminates, latched)
#pragma unroll
          for (int q = 0; q < 4; ++q) hq[q] = ld16_sc(hsrc + aoff[q]);
        }
        if (!got) gave_up = true;
      } else {
        asm volatile("s_waitcnt vmcnt(0)" ::: "memory");
        __builtin_amdgcn_sched_barrier(0);
      }
      // x(t+1) prefetch: issued post-detection, lands during hMFMA+barrier+tail
      if (t + 1 < 512) {
        const size_t xrow = ((size_t)(G * 16 + bb) * 512 + (size_t)(t + 1)) * 1024;
#pragma unroll
        for (int q = 0; q < 4; ++q) {
          const float* xs = xin + xrow + (wid * 4 + q) * 32 + kslot * 8;
          xf[q][0] = *(const f32x4*)xs;
          xf[q][1] = *(const f32x4*)(xs + 4);
        }
      }
      // ---- h-side MFMAs ----
#pragma unroll
      for (int q = 0; q < 4; ++q) {
        union { u32x4 u; f16x8 v; } cu; cu.u = hq[q];
        const int kf = wid * 4 + q;
        f16x8 b0 = *(const f16x8*)&Wl[64 + kf * 2 + 0][lane][0];
        f16x8 b1 = *(const f16x8*)&Wl[64 + kf * 2 + 1][lane][0];
        acc0 = __builtin_amdgcn_mfma_f32_16x16x32_f16(cu.v, b0, acc0, 0, 0, 0);
        acc1 = __builtin_amdgcn_mfma_f32_16x16x32_f16(cu.v, b1, acc1, 0, 0, 0);
      }
    } else {
      // t == 0: no h side; just prefetch x(1)
      const size_t xrow = ((size_t)(G * 16 + bb) * 512 + 1) * 1024;
#pragma unroll
      for (int q = 0; q < 4; ++q) {
        const float* xs = xin + xrow + (wid * 4 + q) * 32 + kslot * 8;
        xf[q][0] = *(const f32x4*)xs;
        xf[q][1] = *(const f32x4*)(xs + 4);
      }
    }
    *(f32x4*)&pl[ppl][wid][0][lane][0] = acc0;
    *(f32x4*)&pl[ppl][wid][1][lane][0] = acc1;
    __syncthreads();  // the ONLY barrier: pl[ppl] ready; waves sprint to t+1
    // ---- owners: reduce, gates, state, publish, outputs ----
    if (tid < 128) {
      float s[4];
#pragma unroll
      for (int g = 0; g < 4; ++g) {
        const int lp = ((g & 1) * 8 + hc) + 16 * (b >> 2);
        const int reg = b & 3;
        float v = bias[g];
#pragma unroll
        for (int w = 0; w < NW; ++w) v += pl[ppl][w][g >> 1][lp][reg];
        s[g] = v;
      }
      const float ig = sigm(s[0]);
      const float fg = sigm(s[1]);
      const float gg = tanh_(s[2]);
      const float og = sigm(s[3]);
      cval = fg * cval + ig * gg;
      const float hval = og * tanh_(cval);
      // publish FIRST: single 2B stego-tagged store, fire-and-forget
      if (t < 511) {
        union { f16 f; uint16_t u; } pk; pk.f = (f16)hval;
        const uint32_t tbp = ((uint32_t)((t + 1) >> 1) + 1u) & 3u;
        const uint32_t bitv = (hc & 1) ? ((tbp >> 1) & 1u) : (tbp & 1u);
        const uint32_t val = ((uint32_t)pk.u & 0xFFFEu) | bitv;
        uint8_t* dst = hb8 + ((size_t)(((t + 1) & 1) * NG + G) << 15)
                     + ((size_t)(r * 16 + b) << 4) + (hc << 1);
        st2_sc(dst, val);
      }
      const float mval = mv_cur;
      if (t + 1 < 512) mv_cur = amask[(size_t)b_glob * 512 + (size_t)(t + 1)];
      // outputs (fire-and-forget; acks land under next step's probe flight)
      const size_t o0 = ((size_t)b_glob * 512 + (size_t)t) * 1024 + (size_t)(hbase + hc);
      out[o0] = hval * mval;                   // hts copy 1
      out[o0 + 16777216u] = hval * mval;       // hts copy 2
      out[o0 + 33554432u] = cval * mval;       // cts
      if (t == myidx) out[50331648u + (size_t)b_glob * 1024 + (size_t)(hbase + hc)] = hval;
    }
  }
}

extern "C" void kernel_launch(void* const* d_in, const int* in_sizes, int n_in,
                              void* d_out, int out_size, void* d_ws, size_t ws_size,
                              hipStream_t stream) {
  const float* xin   = (const float*)d_in[0];
  const float* amask = (const float*)d_in[1];
  const int*   nzidx = (const int*)d_in[2];
  const float* Wx    = (const float*)d_in[3];
  const float* Wh    = (const float*)d_in[4];
  const float* bx    = (const float*)d_in[5];
  const float* bh    = (const float*)d_in[6];
  float* out = (float*)d_out;
  uint32_t* ws = (uint32_t*)d_ws;

  // zero the tagged h-buffer every launch (stale tags differ from fresh expectations)
  hipMemsetAsync(d_ws, 0, HBYTES, stream);

  void* args[] = {(void*)&xin, (void*)&amask, (void*)&nzidx, (void*)&Wx,
                  (void*)&Wh, (void*)&bx, (void*)&bh, (void*)&out, (void*)&ws};
  hipError_t e = hipLaunchCooperativeKernel((const void*)lstm_kernel, dim3(256), dim3(512),
                                            args, 0, stream);
  if (e != hipSuccess) {
    lstm_kernel<<<dim3(256), dim3(512), 0, stream>>>(xin, amask, nzidx, Wx, Wh, bx, bh, out, ws);
  }
}